// Round 10
// baseline (779.731 us; speedup 1.0000x reference)
//
#include <hip/hip_runtime.h>
#include <hip/hip_bf16.h>

#define NUM_HEADS 4
#define HD 256
#define QD 256
#define VD 256
#define B_SZ 32
#define N_NODES 8192
#define NEG_SLOPE 0.2f

typedef short bf16x8 __attribute__((ext_vector_type(8)));
typedef float f32x4 __attribute__((ext_vector_type(4)));

static __device__ __forceinline__ unsigned short f2bf(float f) {
    __hip_bfloat16 h = __float2bfloat16(f);
    return *reinterpret_cast<unsigned short*>(&h);
}

// ---------------------------------------------------------------------------
// Kernel 1: prep
//  blocks 0..31 : hqb[b][col] = query[b]@Wq[:,col] + 2*bq[col]
//  blocks 32..63: pack Wq -> bf16 fragment order
// ---------------------------------------------------------------------------
__global__ __launch_bounds__(256)
void prep_kernel(const float* __restrict__ query,
                 const float* __restrict__ Wq,
                 const float* __restrict__ bq,
                 unsigned short* __restrict__ WqP,
                 float* __restrict__ hqb) {
    int blk = blockIdx.x;
    int tid = threadIdx.x;
    if (blk < 32) {
        int b = blk, col = tid;
        float acc = 2.0f * bq[col];
#pragma unroll 16
        for (int k = 0; k < QD; ++k)
            acc += query[b * QD + k] * Wq[k * HD + col];
        hqb[b * HD + col] = acc;
    } else {
        int idx = blk - 32;
        int kstep = idx >> 2, g = idx & 3;
        int col = tid;
        unsigned short v[8];
#pragma unroll
        for (int j = 0; j < 8; ++j)
            v[j] = f2bf(Wq[(kstep * 32 + g * 8 + j) * HD + col]);
        *reinterpret_cast<uint4*>(WqP + kstep * 8192 + col * 32 + g * 8) =
            *reinterpret_cast<uint4*>(v);
    }
}

// ---------------------------------------------------------------------------
// Kernel 2 (FUSED, persistent free-running waves): grid 256 = (b, 1024-row
// strip). Stage full WqP (128 KB) into LDS ONCE; after that barrier, each
// wave independently loops 8 chunks x 16 rows: value-issue -> MFMA(B from
// LDS) -> epilogue -> ONLINE softmax (running m,l,pa in regs) -> key-prefetch
// -> PV -> cvt. Zero barriers, zero cross-wave deps in the loop. Each wave
// writes its own p_part chunk (chunk id = blk8*8 + w).
// ---------------------------------------------------------------------------
__global__ __launch_bounds__(512)
void fused_kernel(const float* __restrict__ key,
                  const float* __restrict__ value,
                  const unsigned short* __restrict__ WqP,
                  const float* __restrict__ hqb,
                  const float* __restrict__ avec,
                  float* __restrict__ s,
                  float* __restrict__ p_part,
                  float* __restrict__ pml) {
    __shared__ __align__(16) unsigned short wq[65536];   // 128 KB, read-only after stage

    int bid = blockIdx.x;
    int b = bid >> 3, blk8 = bid & 7;
    int tid = threadIdx.x;
    int w = tid >> 6, lane = tid & 63;
    int col16 = lane & 15, g = (lane >> 4) & 3;

    // ---- stage full WqP -> LDS (identical fragment layout), once
    {
        const uint4* src = reinterpret_cast<const uint4*>(WqP);
        uint4* dst = reinterpret_cast<uint4*>(wq);
#pragma unroll
        for (int j = 0; j < 16; ++j)
            dst[tid + j * 512] = src[tid + j * 512];
    }

    float av4[4], hq4[4][4];
#pragma unroll
    for (int ct = 0; ct < 4; ++ct) {
        av4[ct] = avec[ct * 16 + col16];
#pragma unroll
        for (int h = 0; h < 4; ++h)
            hq4[h][ct] = hqb[b * HD + h * 64 + ct * 16 + col16];
    }
    __syncthreads();   // wq ready; LAST barrier in the kernel

    // ---- running online-softmax state (per wave, per head)
    float mr[4] = {-1e30f, -1e30f, -1e30f, -1e30f};
    float lr[4] = {0.f, 0.f, 0.f, 0.f};
    f32x4 pa[4];
#pragma unroll
    for (int h = 0; h < 4; ++h) pa[h] = (f32x4){0.f, 0.f, 0.f, 0.f};

    // ---- prefetch key chunk 0 -> A-fragments
    bf16x8 a[8];
    {
        const float* kb = key + ((size_t)(b * N_NODES + blk8 * 1024 + w * 16 + col16)) * QD + g * 8;
        f32x4 kf[16];
#pragma unroll
        for (int ks = 0; ks < 8; ++ks) {
            kf[ks * 2]     = *reinterpret_cast<const f32x4*>(kb + ks * 32);
            kf[ks * 2 + 1] = *reinterpret_cast<const f32x4*>(kb + ks * 32 + 4);
        }
#pragma unroll
        for (int ks = 0; ks < 8; ++ks) {
            unsigned int u0, u1, u2, u3;
            asm("v_cvt_pk_bf16_f32 %0, %1, %2" : "=v"(u0) : "v"(kf[ks*2][0]), "v"(kf[ks*2][1]));
            asm("v_cvt_pk_bf16_f32 %0, %1, %2" : "=v"(u1) : "v"(kf[ks*2][2]), "v"(kf[ks*2][3]));
            asm("v_cvt_pk_bf16_f32 %0, %1, %2" : "=v"(u2) : "v"(kf[ks*2+1][0]), "v"(kf[ks*2+1][1]));
            asm("v_cvt_pk_bf16_f32 %0, %1, %2" : "=v"(u3) : "v"(kf[ks*2+1][2]), "v"(kf[ks*2+1][3]));
            uint4 t = {u0, u1, u2, u3};
            a[ks] = *reinterpret_cast<bf16x8*>(&t);
        }
    }

    for (int c = 0; c < 8; ++c) {
        int n0 = blk8 * 1024 + c * 128 + w * 16;

        // ---- issue value loads (arrive during MFMA+softmax)
        f32x4 vv[16];
        {
            const float* vb = value + ((size_t)(b * N_NODES + n0)) * VD + lane * 4;
#pragma unroll
            for (int n = 0; n < 16; ++n)
                vv[n] = *reinterpret_cast<const f32x4*>(vb + (size_t)n * VD);
        }

        // ---- per-head MFMA + epilogue + online softmax update
        float epv[4][4];
#pragma unroll
        for (int h = 0; h < 4; ++h) {
            f32x4 acc[4];
#pragma unroll
            for (int ct = 0; ct < 4; ++ct) acc[ct] = (f32x4){0.f, 0.f, 0.f, 0.f};
#pragma unroll
            for (int ks = 0; ks < 8; ++ks) {
                const unsigned short* wp = wq + ks * 8192 + h * 2048 + g * 8;
#pragma unroll
                for (int ct = 0; ct < 4; ++ct) {
                    bf16x8 bf = *reinterpret_cast<const bf16x8*>(wp + (ct * 16 + col16) * 32);
                    acc[ct] = __builtin_amdgcn_mfma_f32_16x16x32_bf16(a[ks], bf, acc[ct], 0, 0, 0);
                }
            }
            float part[4] = {0.f, 0.f, 0.f, 0.f};
#pragma unroll
            for (int ct = 0; ct < 4; ++ct) {
#pragma unroll
                for (int r = 0; r < 4; ++r) {
                    float pre = acc[ct][r] + hq4[h][ct];
                    float t = fmaxf(pre, NEG_SLOPE * pre);
                    part[r] += av4[ct] * t;
                }
            }
#pragma unroll
            for (int off = 1; off < 16; off <<= 1)
#pragma unroll
                for (int r = 0; r < 4; ++r)
                    part[r] += __shfl_xor(part[r], off, 64);
            if (col16 == 0) {
                float4 sv4 = {part[0], part[1], part[2], part[3]};
                *reinterpret_cast<float4*>(
                    s + ((size_t)(b * NUM_HEADS + h)) * N_NODES + n0 + g * 4) = sv4;
            }
            // chunk max over this wave's 16 rows
            float mc = fmaxf(fmaxf(part[0], part[1]), fmaxf(part[2], part[3]));
            mc = fmaxf(mc, __shfl_xor(mc, 16, 64));
            mc = fmaxf(mc, __shfl_xor(mc, 32, 64));
            float mnew = fmaxf(mr[h], mc);
            float lc = 0.f;
#pragma unroll
            for (int r = 0; r < 4; ++r) { epv[h][r] = __expf(part[r] - mnew); lc += epv[h][r]; }
            lc += __shfl_xor(lc, 16, 64);
            lc += __shfl_xor(lc, 32, 64);
            float sc_ = __expf(mr[h] - mnew);
            pa[h] *= sc_;
            lr[h] = lr[h] * sc_ + lc;
            mr[h] = mnew;
        }

        // ---- issue next-chunk key loads (arrive during PV)
        f32x4 kf[16];
        if (c < 7) {
            const float* kb = key + ((size_t)(b * N_NODES + n0 + 128 + col16)) * QD + g * 8;
#pragma unroll
            for (int ks = 0; ks < 8; ++ks) {
                kf[ks * 2]     = *reinterpret_cast<const f32x4*>(kb + ks * 32);
                kf[ks * 2 + 1] = *reinterpret_cast<const f32x4*>(kb + ks * 32 + 4);
            }
        }

        // ---- PV: broadcast exp-scores, accumulate into running pa
#pragma unroll
        for (int n = 0; n < 16; ++n) {
#pragma unroll
            for (int h = 0; h < 4; ++h) {
                float e = __shfl(epv[h][n & 3], (n >> 2) * 16, 64);
                pa[h] += e * vv[n];
            }
        }

        // ---- convert key for next chunk
        if (c < 7) {
#pragma unroll
            for (int ks = 0; ks < 8; ++ks) {
                unsigned int u0, u1, u2, u3;
                asm("v_cvt_pk_bf16_f32 %0, %1, %2" : "=v"(u0) : "v"(kf[ks*2][0]), "v"(kf[ks*2][1]));
                asm("v_cvt_pk_bf16_f32 %0, %1, %2" : "=v"(u1) : "v"(kf[ks*2][2]), "v"(kf[ks*2][3]));
                asm("v_cvt_pk_bf16_f32 %0, %1, %2" : "=v"(u2) : "v"(kf[ks*2+1][0]), "v"(kf[ks*2+1][1]));
                asm("v_cvt_pk_bf16_f32 %0, %1, %2" : "=v"(u3) : "v"(kf[ks*2+1][2]), "v"(kf[ks*2+1][3]));
                uint4 t = {u0, u1, u2, u3};
                a[ks] = *reinterpret_cast<bf16x8*>(&t);
            }
        }
    }

    // ---- per-wave output (chunk id = blk8*8 + w), no barrier needed
    int chunkid = b * 64 + blk8 * 8 + w;
    float* pp = p_part + (size_t)chunkid * 1024;
#pragma unroll
    for (int h = 0; h < 4; ++h)
        *reinterpret_cast<f32x4*>(pp + h * 256 + lane * 4) = pa[h];
    if (lane == 0) {
#pragma unroll
        for (int h = 0; h < 4; ++h) {
            pml[(size_t)chunkid * 8 + h] = mr[h];
            pml[(size_t)chunkid * 8 + 4 + h] = lr[h];
        }
    }
}

// ---------------------------------------------------------------------------
// Kernel 3: final. Per (b,h): global M,L over 64 wave-chunks; rescale-reduce
// p_part; @Wv + bias + relu; emit (M, invL) for epass.
// ---------------------------------------------------------------------------
__global__ __launch_bounds__(256)
void final_kernel(const float* __restrict__ p_part,
                  const float* __restrict__ pml,
                  const float* __restrict__ Wv,
                  const float* __restrict__ bv,
                  float* __restrict__ hout,
                  float* __restrict__ sc) {
    int bh = blockIdx.x;
    int b = bh >> 2, h = bh & 3;
    int tid = threadIdx.x;
    int wv = tid >> 6, lane = tid & 63;

    float mc = -1e30f, lc = 0.f;
    if (tid < 64) {
        mc = pml[((size_t)(b * 64 + tid)) * 8 + h];
        lc = pml[((size_t)(b * 64 + tid)) * 8 + 4 + h];
    }

    __shared__ float r4a[4], r4b[4];
    __shared__ float wfs[64];
    float M = mc;
#pragma unroll
    for (int off = 1; off < 64; off <<= 1) M = fmaxf(M, __shfl_xor(M, off, 64));
    if (lane == 0) r4a[wv] = M;
    __syncthreads();
    M = fmaxf(fmaxf(r4a[0], r4a[1]), fmaxf(r4a[2], r4a[3]));

    float wf = (tid < 64) ? __expf(mc - M) : 0.f;
    if (tid < 64) wfs[tid] = wf;
    float Lp = wf * lc;
#pragma unroll
    for (int off = 1; off < 64; off <<= 1) Lp += __shfl_xor(Lp, off, 64);
    if (lane == 0) r4b[wv] = Lp;
    __syncthreads();
    float L = r4b[0] + r4b[1] + r4b[2] + r4b[3];
    float invL = 1.0f / L;
    if (tid == 0) {
        sc[bh * 2] = M;
        sc[bh * 2 + 1] = invL;
    }

    float acc = 0.f;
    const float* pp = p_part + ((size_t)(b * 64)) * 1024 + h * 256 + tid;
#pragma unroll 8
    for (int c = 0; c < 64; ++c)
        acc += wfs[c] * pp[(size_t)c * 1024];
    __shared__ float ps[256];
    ps[tid] = acc * invL;
    __syncthreads();

    int d = tid & 63, kr = tid >> 6;
    float a2 = 0.f;
#pragma unroll 8
    for (int k = kr * 64; k < kr * 64 + 64; ++k)
        a2 += ps[k] * Wv[k * HD + h * 64 + d];
    __shared__ float rs[4][64];
    rs[kr][d] = a2;
    __syncthreads();
    if (tid < 64) {
        float o = bv[h * 64 + tid] + rs[0][tid] + rs[1][tid] + rs[2][tid] + rs[3][tid];
        hout[b * HD + h * 64 + tid] = fmaxf(o, 0.f);
    }
}

// ---------------------------------------------------------------------------
// Kernel 4: e-pass. e_out[b,n,h] = exp(s[b,h,n]-M)*invL.
// ---------------------------------------------------------------------------
__global__ __launch_bounds__(256)
void epass_kernel(const float* __restrict__ s,
                  const float* __restrict__ sc,
                  float* __restrict__ e_out) {
    int bid = blockIdx.x;
    int b = bid >> 5, t = bid & 31;
    int n = t * 256 + threadIdx.x;
    float4 ev;
#pragma unroll
    for (int h = 0; h < 4; ++h) {
        float M = sc[(b * 4 + h) * 2];
        float invL = sc[(b * 4 + h) * 2 + 1];
        float sv = s[((size_t)(b * 4 + h)) * N_NODES + n];
        (&ev.x)[h] = __expf(sv - M) * invL;
    }
    *reinterpret_cast<float4*>(e_out + ((size_t)(b * N_NODES + n)) * 4) = ev;
}

extern "C" void kernel_launch(void* const* d_in, const int* in_sizes, int n_in,
                              void* d_out, int out_size, void* d_ws, size_t ws_size,
                              hipStream_t stream) {
    const float* query = (const float*)d_in[0];
    const float* key   = (const float*)d_in[1];
    const float* value = (const float*)d_in[2];
    const float* Wq    = (const float*)d_in[3];
    const float* bq    = (const float*)d_in[4];
    const float* Wv    = (const float*)d_in[5];
    const float* bv    = (const float*)d_in[6];
    const float* avec  = (const float*)d_in[7];
    float* out = (float*)d_out;

    char* ws = (char*)d_ws;
    unsigned short* WqP = (unsigned short*)ws;               // 128 KB
    float* hqb    = (float*)(ws + 131072);                   // 32 KB
    float* s      = (float*)(ws + 163840);                   // 4 MB
    float* pml    = (float*)(ws + 4358144);                  // 64 KB
    float* sc     = (float*)(ws + 4423680);                  // 4 KB
    float* p_part = (float*)(ws + 4427776);                  // 8 MB

    prep_kernel<<<64, 256, 0, stream>>>(query, Wq, bq, WqP, hqb);
    fused_kernel<<<256, 512, 0, stream>>>(key, value, WqP, hqb, avec, s, p_part, pml);
    final_kernel<<<B_SZ * NUM_HEADS, 256, 0, stream>>>(p_part, pml, Wv, bv, out, sc);
    epass_kernel<<<B_SZ * 32, 256, 0, stream>>>(s, sc, out + B_SZ * HD);
}

// Round 11
// 158.330 us; speedup vs baseline: 4.9247x; 4.9247x over previous
//
#include <hip/hip_runtime.h>
#include <hip/hip_bf16.h>

#define NUM_HEADS 4
#define HD 256
#define QD 256
#define VD 256
#define B_SZ 32
#define N_NODES 8192
#define NEG_SLOPE 0.2f

typedef short bf16x8 __attribute__((ext_vector_type(8)));
typedef float f32x4 __attribute__((ext_vector_type(4)));

static __device__ __forceinline__ unsigned short f2bf(float f) {
    __hip_bfloat16 h = __float2bfloat16(f);
    return *reinterpret_cast<unsigned short*>(&h);
}

// ---------------------------------------------------------------------------
// Kernel 1: prep
//  blocks 0..31 : hqb[b][col] = query[b]@Wq[:,col] + 2*bq[col]
//  blocks 32..63: pack Wq -> bf16, SWIZZLED fragment order:
//    WqP[ks*8192 + h*2048 + ct*512 + (g*16+col16)*8 + j]
//      = bf16( Wq[ks*32 + g*8 + j][h*64 + ct*16 + col16] )
//  -> a wave's ds_read_b128 for (ks,h,ct) is lane-linear over 1KB
//     (conflict-free, m134 pattern).
// ---------------------------------------------------------------------------
__global__ __launch_bounds__(256)
void prep_kernel(const float* __restrict__ query,
                 const float* __restrict__ Wq,
                 const float* __restrict__ bq,
                 unsigned short* __restrict__ WqP,
                 float* __restrict__ hqb) {
    int blk = blockIdx.x;
    int tid = threadIdx.x;
    if (blk < 32) {
        int b = blk, col = tid;
        float acc = 2.0f * bq[col];
#pragma unroll 16
        for (int k = 0; k < QD; ++k)
            acc += query[b * QD + k] * Wq[k * HD + col];
        hqb[b * HD + col] = acc;
    } else {
        int idx = blk - 32;
        int kstep = idx >> 2, g = idx & 3;
        int col = tid;                 // global column 0..255
        int h = col >> 6, ct = (col >> 4) & 3, col16 = col & 15;
        unsigned short v[8];
#pragma unroll
        for (int j = 0; j < 8; ++j)
            v[j] = f2bf(Wq[(kstep * 32 + g * 8 + j) * HD + col]);
        *reinterpret_cast<uint4*>(
            WqP + kstep * 8192 + h * 2048 + ct * 512 + (g * 16 + col16) * 8) =
            *reinterpret_cast<uint4*>(v);
    }
}

// ---------------------------------------------------------------------------
// Kernel 2 (FUSED, persistent free-running waves, spill-free):
// grid 256 = (b, 1024-row strip), 512 threads, 1 block/CU (128 KB LDS).
// Stage WqP once -> barrier -> each wave loops 8 chunks x 16 rows with ZERO
// barriers: {issue key+value bursts, cvt key, MFMA (B conflict-free from
// LDS), epilogue, online softmax, PV}. Per-wave p_part write at end.
// __launch_bounds__(512,2): VGPR ceiling 256 -> no spill (R10 lesson).
// ---------------------------------------------------------------------------
__global__ __launch_bounds__(512, 2)
void fused_kernel(const float* __restrict__ key,
                  const float* __restrict__ value,
                  const unsigned short* __restrict__ WqP,
                  const float* __restrict__ hqb,
                  const float* __restrict__ avec,
                  float* __restrict__ s,
                  float* __restrict__ p_part,
                  float* __restrict__ pml) {
    __shared__ __align__(16) unsigned short wq[65536];   // 128 KB, read-only after stage

    int bid = blockIdx.x;
    int b = bid >> 3, blk8 = bid & 7;
    int tid = threadIdx.x;
    int w = tid >> 6, lane = tid & 63;
    int col16 = lane & 15, g = (lane >> 4) & 3;

    // ---- stage full WqP -> LDS (lane-linear copy), once
    {
        const uint4* src = reinterpret_cast<const uint4*>(WqP);
        uint4* dst = reinterpret_cast<uint4*>(wq);
#pragma unroll
        for (int j = 0; j < 16; ++j)
            dst[tid + j * 512] = src[tid + j * 512];
    }
    float av4[4];
#pragma unroll
    for (int ct = 0; ct < 4; ++ct) av4[ct] = avec[ct * 16 + col16];
    __syncthreads();   // wq ready; LAST barrier in the kernel

    // ---- running online-softmax state (per wave, per head)
    float mr[4] = {-1e30f, -1e30f, -1e30f, -1e30f};
    float lr[4] = {0.f, 0.f, 0.f, 0.f};
    f32x4 pa[4];
#pragma unroll
    for (int h = 0; h < 4; ++h) pa[h] = (f32x4){0.f, 0.f, 0.f, 0.f};

    for (int c = 0; c < 8; ++c) {
        int n0 = blk8 * 1024 + c * 128 + w * 16;

        // ---- issue key burst (16 x 16B) and value burst (16 x 16B) together:
        //      up to 32 KB outstanding per wave before first use
        f32x4 kf[16];
        {
            const float* kb = key + ((size_t)(b * N_NODES + n0 + col16)) * QD + g * 8;
#pragma unroll
            for (int ks = 0; ks < 8; ++ks) {
                kf[ks * 2]     = *reinterpret_cast<const f32x4*>(kb + ks * 32);
                kf[ks * 2 + 1] = *reinterpret_cast<const f32x4*>(kb + ks * 32 + 4);
            }
        }
        f32x4 vv[16];
        {
            const float* vb = value + ((size_t)(b * N_NODES + n0)) * VD + lane * 4;
#pragma unroll
            for (int n = 0; n < 16; ++n)
                vv[n] = *reinterpret_cast<const f32x4*>(vb + (size_t)n * VD);
        }

        // ---- cvt key -> A-fragments (kf dies here)
        bf16x8 a[8];
#pragma unroll
        for (int ks = 0; ks < 8; ++ks) {
            unsigned int u0, u1, u2, u3;
            asm("v_cvt_pk_bf16_f32 %0, %1, %2" : "=v"(u0) : "v"(kf[ks*2][0]), "v"(kf[ks*2][1]));
            asm("v_cvt_pk_bf16_f32 %0, %1, %2" : "=v"(u1) : "v"(kf[ks*2][2]), "v"(kf[ks*2][3]));
            asm("v_cvt_pk_bf16_f32 %0, %1, %2" : "=v"(u2) : "v"(kf[ks*2+1][0]), "v"(kf[ks*2+1][1]));
            asm("v_cvt_pk_bf16_f32 %0, %1, %2" : "=v"(u3) : "v"(kf[ks*2+1][2]), "v"(kf[ks*2+1][3]));
            uint4 t = {u0, u1, u2, u3};
            a[ks] = *reinterpret_cast<bf16x8*>(&t);
        }

        // ---- per-head MFMA (conflict-free B from LDS) + epilogue + online SM
        float epv[4][4];
#pragma unroll
        for (int h = 0; h < 4; ++h) {
            f32x4 acc[4];
#pragma unroll
            for (int ct = 0; ct < 4; ++ct) acc[ct] = (f32x4){0.f, 0.f, 0.f, 0.f};
#pragma unroll
            for (int ks = 0; ks < 8; ++ks) {
                const unsigned short* wp = wq + ks * 8192 + h * 2048 + (g * 16 + col16) * 8;
#pragma unroll
                for (int ct = 0; ct < 4; ++ct) {
                    bf16x8 bf = *reinterpret_cast<const bf16x8*>(wp + ct * 512);
                    acc[ct] = __builtin_amdgcn_mfma_f32_16x16x32_bf16(a[ks], bf, acc[ct], 0, 0, 0);
                }
            }
            float part[4] = {0.f, 0.f, 0.f, 0.f};
#pragma unroll
            for (int ct = 0; ct < 4; ++ct) {
                float hq_ = hqb[b * HD + h * 64 + ct * 16 + col16];
#pragma unroll
                for (int r = 0; r < 4; ++r) {
                    float pre = acc[ct][r] + hq_;
                    float t = fmaxf(pre, NEG_SLOPE * pre);
                    part[r] += av4[ct] * t;
                }
            }
#pragma unroll
            for (int off = 1; off < 16; off <<= 1)
#pragma unroll
                for (int r = 0; r < 4; ++r)
                    part[r] += __shfl_xor(part[r], off, 64);
            if (col16 == 0) {
                float4 sv4 = {part[0], part[1], part[2], part[3]};
                *reinterpret_cast<float4*>(
                    s + ((size_t)(b * NUM_HEADS + h)) * N_NODES + n0 + g * 4) = sv4;
            }
            float mc = fmaxf(fmaxf(part[0], part[1]), fmaxf(part[2], part[3]));
            mc = fmaxf(mc, __shfl_xor(mc, 16, 64));
            mc = fmaxf(mc, __shfl_xor(mc, 32, 64));
            float mnew = fmaxf(mr[h], mc);
            float lc = 0.f;
#pragma unroll
            for (int r = 0; r < 4; ++r) { epv[h][r] = __expf(part[r] - mnew); lc += epv[h][r]; }
            lc += __shfl_xor(lc, 16, 64);
            lc += __shfl_xor(lc, 32, 64);
            float sc_ = __expf(mr[h] - mnew);
            pa[h] *= sc_;
            lr[h] = lr[h] * sc_ + lc;
            mr[h] = mnew;
        }

        // ---- PV: broadcast exp-scores, accumulate into running pa (vv dies)
#pragma unroll
        for (int n = 0; n < 16; ++n) {
#pragma unroll
            for (int h = 0; h < 4; ++h) {
                float e = __shfl(epv[h][n & 3], (n >> 2) * 16, 64);
                pa[h] += e * vv[n];
            }
        }
    }

    // ---- per-wave output (chunk id = blk8*8 + w), no barrier needed
    int chunkid = b * 64 + blk8 * 8 + w;
    float* pp = p_part + (size_t)chunkid * 1024;
#pragma unroll
    for (int h = 0; h < 4; ++h)
        *reinterpret_cast<f32x4*>(pp + h * 256 + lane * 4) = pa[h];
    if (lane == 0) {
#pragma unroll
        for (int h = 0; h < 4; ++h) {
            pml[(size_t)chunkid * 8 + h] = mr[h];
            pml[(size_t)chunkid * 8 + 4 + h] = lr[h];
        }
    }
}

// ---------------------------------------------------------------------------
// Kernel 3: final. Per (b,h): global M,L over 64 wave-chunks; rescale-reduce
// p_part; @Wv + bias + relu; emit (M, invL) for epass.
// ---------------------------------------------------------------------------
__global__ __launch_bounds__(256)
void final_kernel(const float* __restrict__ p_part,
                  const float* __restrict__ pml,
                  const float* __restrict__ Wv,
                  const float* __restrict__ bv,
                  float* __restrict__ hout,
                  float* __restrict__ sc) {
    int bh = blockIdx.x;
    int b = bh >> 2, h = bh & 3;
    int tid = threadIdx.x;
    int wv = tid >> 6, lane = tid & 63;

    float mc = -1e30f, lc = 0.f;
    if (tid < 64) {
        mc = pml[((size_t)(b * 64 + tid)) * 8 + h];
        lc = pml[((size_t)(b * 64 + tid)) * 8 + 4 + h];
    }

    __shared__ float r4a[4], r4b[4];
    __shared__ float wfs[64];
    float M = mc;
#pragma unroll
    for (int off = 1; off < 64; off <<= 1) M = fmaxf(M, __shfl_xor(M, off, 64));
    if (lane == 0) r4a[wv] = M;
    __syncthreads();
    M = fmaxf(fmaxf(r4a[0], r4a[1]), fmaxf(r4a[2], r4a[3]));

    float wf = (tid < 64) ? __expf(mc - M) : 0.f;
    if (tid < 64) wfs[tid] = wf;
    float Lp = wf * lc;
#pragma unroll
    for (int off = 1; off < 64; off <<= 1) Lp += __shfl_xor(Lp, off, 64);
    if (lane == 0) r4b[wv] = Lp;
    __syncthreads();
    float L = r4b[0] + r4b[1] + r4b[2] + r4b[3];
    float invL = 1.0f / L;
    if (tid == 0) {
        sc[bh * 2] = M;
        sc[bh * 2 + 1] = invL;
    }

    float acc = 0.f;
    const float* pp = p_part + ((size_t)(b * 64)) * 1024 + h * 256 + tid;
#pragma unroll 8
    for (int c = 0; c < 64; ++c)
        acc += wfs[c] * pp[(size_t)c * 1024];
    __shared__ float ps[256];
    ps[tid] = acc * invL;
    __syncthreads();

    int d = tid & 63, kr = tid >> 6;
    float a2 = 0.f;
#pragma unroll 8
    for (int k = kr * 64; k < kr * 64 + 64; ++k)
        a2 += ps[k] * Wv[k * HD + h * 64 + d];
    __shared__ float rs[4][64];
    rs[kr][d] = a2;
    __syncthreads();
    if (tid < 64) {
        float o = bv[h * 64 + tid] + rs[0][tid] + rs[1][tid] + rs[2][tid] + rs[3][tid];
        hout[b * HD + h * 64 + tid] = fmaxf(o, 0.f);
    }
}

// ---------------------------------------------------------------------------
// Kernel 4: e-pass. e_out[b,n,h] = exp(s[b,h,n]-M)*invL.
// ---------------------------------------------------------------------------
__global__ __launch_bounds__(256)
void epass_kernel(const float* __restrict__ s,
                  const float* __restrict__ sc,
                  float* __restrict__ e_out) {
    int bid = blockIdx.x;
    int b = bid >> 5, t = bid & 31;
    int n = t * 256 + threadIdx.x;
    float4 ev;
#pragma unroll
    for (int h = 0; h < 4; ++h) {
        float M = sc[(b * 4 + h) * 2];
        float invL = sc[(b * 4 + h) * 2 + 1];
        float sv = s[((size_t)(b * 4 + h)) * N_NODES + n];
        (&ev.x)[h] = __expf(sv - M) * invL;
    }
    *reinterpret_cast<float4*>(e_out + ((size_t)(b * N_NODES + n)) * 4) = ev;
}

extern "C" void kernel_launch(void* const* d_in, const int* in_sizes, int n_in,
                              void* d_out, int out_size, void* d_ws, size_t ws_size,
                              hipStream_t stream) {
    const float* query = (const float*)d_in[0];
    const float* key   = (const float*)d_in[1];
    const float* value = (const float*)d_in[2];
    const float* Wq    = (const float*)d_in[3];
    const float* bq    = (const float*)d_in[4];
    const float* Wv    = (const float*)d_in[5];
    const float* bv    = (const float*)d_in[6];
    const float* avec  = (const float*)d_in[7];
    float* out = (float*)d_out;

    char* ws = (char*)d_ws;
    unsigned short* WqP = (unsigned short*)ws;               // 128 KB
    float* hqb    = (float*)(ws + 131072);                   // 32 KB
    float* s      = (float*)(ws + 163840);                   // 4 MB
    float* pml    = (float*)(ws + 4358144);                  // 64 KB
    float* sc     = (float*)(ws + 4423680);                  // 4 KB
    float* p_part = (float*)(ws + 4427776);                  // 8 MB

    prep_kernel<<<64, 256, 0, stream>>>(query, Wq, bq, WqP, hqb);
    fused_kernel<<<256, 512, 0, stream>>>(key, value, WqP, hqb, avec, s, p_part, pml);
    final_kernel<<<B_SZ * NUM_HEADS, 256, 0, stream>>>(p_part, pml, Wv, bv, out, sc);
    epass_kernel<<<B_SZ * 32, 256, 0, stream>>>(s, sc, out + B_SZ * HD);
}